// Round 10
// baseline (203.953 us; speedup 1.0000x reference)
//
#include <hip/hip_runtime.h>
#include <hip/hip_bf16.h>

#define B_  2
#define N_  2048
#define C_  1024
#define H_  16
#define HD_ 64
#define QSZ (B_*N_*C_)       // elements per q/k/v buffer
#define QSCALE 0.18033688011112042f   // 0.125 * log2(e): softmax in exp2 domain

typedef __attribute__((ext_vector_type(8))) short short8;            // 8 bf16
typedef __attribute__((ext_vector_type(4))) float floatx4;
typedef __attribute__((ext_vector_type(4))) unsigned short ushort4v; // 4 bf16

__device__ __forceinline__ unsigned short f2bf(float f) {
    unsigned int u = __builtin_bit_cast(unsigned int, f);
    u += 0x7fff + ((u >> 16) & 1);          // round-to-nearest-even
    return (unsigned short)(u >> 16);
}
__device__ __forceinline__ float bf2f(unsigned short h) {
    return __builtin_bit_cast(float, (unsigned int)h << 16);
}
// pack two fp32 -> two RNE bf16 in one u32 (lo = a, hi = b) via v_perm_b32
__device__ __forceinline__ unsigned int pk2bf(float a, float b) {
    unsigned int ua = __builtin_bit_cast(unsigned int, a);
    unsigned int ub = __builtin_bit_cast(unsigned int, b);
    ua += 0x7fff + ((ua >> 16) & 1);
    ub += 0x7fff + ((ub >> 16) & 1);
    return __builtin_amdgcn_perm(ub, ua, 0x07060302);
}

// async global->LDS, 16 B per lane; LDS dest = wave-uniform base + lane*16
__device__ __forceinline__ void g2l16(const void* g, void* l) {
    __builtin_amdgcn_global_load_lds(
        (const __attribute__((address_space(1))) void*)g,
        (__attribute__((address_space(3))) void*)l, 16, 0, 0);
}

// ---------------------------------------------------------------------------
// pack fp32 -> bf16, same layout
// ---------------------------------------------------------------------------
__global__ __launch_bounds__(256) void pack_bf16_kernel(
    const float* __restrict__ src, unsigned short* __restrict__ dst)
{
    const int i = blockIdx.x * 256 + threadIdx.x;
    float4 v = ((const float4*)src)[i];
    ushort4 o = {f2bf(v.x), f2bf(v.y), f2bf(v.z), f2bf(v.w)};
    ((ushort4*)dst)[i] = o;
}

// ---------------------------------------------------------------------------
// transpose + pack BOTH weights in one launch:
// bx < 96: W_qkv [1024][3072] -> wqt [3072][1024]
// bx >= 96: W_proj [1024][1024] -> wpt [1024][1024]
// ---------------------------------------------------------------------------
__global__ __launch_bounds__(256) void transpose_pack2_kernel(
    const float* __restrict__ Wq, unsigned short* __restrict__ Wqt,
    const float* __restrict__ Wp, unsigned short* __restrict__ Wpt)
{
    __shared__ unsigned short tl[32][34];
    const bool isq = blockIdx.x < 96;
    const int bx = isq ? blockIdx.x : blockIdx.x - 96;
    const int Nd = isq ? 3072 : 1024;
    const float* W = isq ? Wq : Wp;
    unsigned short* Wt = isq ? Wqt : Wpt;
    const int r  = threadIdx.x >> 3;
    const int c4 = (threadIdx.x & 7) * 4;
    const int n0 = bx * 32, k0 = blockIdx.y * 32;
    float4 v = *(const float4*)&W[(size_t)(k0 + r) * Nd + n0 + c4];
    tl[r][c4 + 0] = f2bf(v.x); tl[r][c4 + 1] = f2bf(v.y);
    tl[r][c4 + 2] = f2bf(v.z); tl[r][c4 + 3] = f2bf(v.w);
    __syncthreads();
    ushort4 o = {tl[c4 + 0][r], tl[c4 + 1][r], tl[c4 + 2][r], tl[c4 + 3][r]};
    *(ushort4*)&Wt[(size_t)(n0 + r) * 1024 + k0 + c4] = o;
}

// ---------------------------------------------------------------------------
// bf16 MFMA GEMM core (m97 structure): 128x128 tile, BK=32, 4 waves
// ---------------------------------------------------------------------------
#define GEMM_CORE(A_, Bt_, Kd_, row0_, col0_)                                 \
    __shared__ unsigned short As[128 * 32];                                   \
    __shared__ unsigned short Bs[128 * 32];                                   \
    const int t    = threadIdx.x;                                             \
    const int lane = t & 63;                                                  \
    const int w    = t >> 6;                                                  \
    const int l15  = lane & 15;                                               \
    const int quad = lane >> 4;                                               \
    const int wm   = w >> 1, wn = w & 1;                                      \
    size_t aOff = (size_t)(row0_ + w * 16 + (lane >> 2)) * Kd_ + (lane & 3) * 8; \
    size_t bOff = (size_t)(col0_ + w * 16 + (lane >> 2)) * Kd_ + (lane & 3) * 8; \
    floatx4 acc[4][4];                                                        \
    _Pragma("unroll")                                                         \
    for (int i = 0; i < 4; ++i)                                               \
        _Pragma("unroll")                                                     \
        for (int j = 0; j < 4; ++j) acc[i][j] = floatx4{0.f, 0.f, 0.f, 0.f};  \
    for (int k0 = 0; k0 < Kd_; k0 += 32) {                                    \
        _Pragma("unroll")                                                     \
        for (int c = 0; c < 2; ++c) {                                         \
            g2l16(&A_[aOff + (size_t)c * 64 * Kd_ + k0],                      \
                  &As[(w * 16 + c * 64) * 32]);                               \
            g2l16(&Bt_[bOff + (size_t)c * 64 * Kd_ + k0],                     \
                  &Bs[(w * 16 + c * 64) * 32]);                               \
        }                                                                     \
        __syncthreads();                                                      \
        short8 af[4], bf[4];                                                  \
        _Pragma("unroll")                                                     \
        for (int i = 0; i < 4; ++i)                                           \
            af[i] = *(const short8*)&As[(wm * 64 + i * 16 + l15) * 32 + quad * 8]; \
        _Pragma("unroll")                                                     \
        for (int j = 0; j < 4; ++j)                                           \
            bf[j] = *(const short8*)&Bs[(wn * 64 + j * 16 + l15) * 32 + quad * 8]; \
        _Pragma("unroll")                                                     \
        for (int i = 0; i < 4; ++i)                                           \
            _Pragma("unroll")                                                 \
            for (int j = 0; j < 4; ++j)                                       \
                acc[i][j] = __builtin_amdgcn_mfma_f32_16x16x32_bf16(          \
                    af[i], bf[j], acc[i][j], 0, 0, 0);                        \
        __syncthreads();                                                      \
    }

// ---------------------------------------------------------------------------
// Kernel 1: qkv = x @ W_qkv with FUSED per-head LayerNorm on q,k (fp32 math
// on accumulators, before bf16 rounding). q scaled by 0.125*log2(e).
// ---------------------------------------------------------------------------
__global__ __launch_bounds__(256) void gemm_qkv_kernel(
    const unsigned short* __restrict__ X,    // [4096][1024] bf16
    const unsigned short* __restrict__ Wt,   // [3072][1024] bf16 (W^T)
    const float* __restrict__ qn_w, const float* __restrict__ qn_b,
    const float* __restrict__ kn_w, const float* __restrict__ kn_b,
    unsigned short* __restrict__ qb, unsigned short* __restrict__ kb,
    unsigned short* __restrict__ vb)
{
    const int row0 = blockIdx.y * 128;
    const int col0 = blockIdx.x * 128;
    GEMM_CORE(X, Wt, 1024, row0, col0)
    const int which = col0 >> 10;            // 0=q 1=k 2=v, uniform per block
    const int h = ((col0 & 1023) >> 6) + wn; // head index for this wave
    if (which == 2) {
        #pragma unroll
        for (int j = 0; j < 4; ++j) {
            const int d = j * 16 + l15;
            #pragma unroll
            for (int i = 0; i < 4; ++i) {
                #pragma unroll
                for (int r = 0; r < 4; ++r) {
                    const int grow = row0 + wm * 64 + i * 16 + quad * 4 + r;
                    const int bidx = grow >> 11, n = grow & 2047;
                    vb[(((size_t)(bidx * H_ + h) * N_ + n) * HD_) + d] =
                        f2bf(acc[i][j][r]);
                }
            }
        }
    } else {
        const float* wt = (which == 0) ? qn_w : kn_w;
        const float* bi = (which == 0) ? qn_b : kn_b;
        unsigned short* dstbuf = (which == 0) ? qb : kb;
        float w4[4], b4[4];
        #pragma unroll
        for (int j = 0; j < 4; ++j) {
            w4[j] = wt[j * 16 + l15];
            b4[j] = bi[j * 16 + l15];
        }
        #pragma unroll
        for (int i = 0; i < 4; ++i) {
            #pragma unroll
            for (int r = 0; r < 4; ++r) {
                float v0 = acc[i][0][r], v1 = acc[i][1][r],
                      v2 = acc[i][2][r], v3 = acc[i][3][r];
                float s = (v0 + v1) + (v2 + v3);
                #pragma unroll
                for (int o = 1; o < 16; o <<= 1) s += __shfl_xor(s, o);
                const float mu = s * (1.0f / 64.0f);
                const float d0 = v0 - mu, d1 = v1 - mu,
                            d2 = v2 - mu, d3 = v3 - mu;
                float s2 = (d0 * d0 + d1 * d1) + (d2 * d2 + d3 * d3);
                #pragma unroll
                for (int o = 1; o < 16; o <<= 1) s2 += __shfl_xor(s2, o);
                const float rstd = rsqrtf(s2 * (1.0f / 64.0f) + 1e-5f);
                float y0 = d0 * rstd * w4[0] + b4[0];
                float y1 = d1 * rstd * w4[1] + b4[1];
                float y2 = d2 * rstd * w4[2] + b4[2];
                float y3 = d3 * rstd * w4[3] + b4[3];
                if (which == 0) {
                    y0 *= QSCALE; y1 *= QSCALE; y2 *= QSCALE; y3 *= QSCALE;
                }
                const int grow = row0 + wm * 64 + i * 16 + quad * 4 + r;
                const int bidx = grow >> 11, n = grow & 2047;
                unsigned short* dp =
                    &dstbuf[(((size_t)(bidx * H_ + h) * N_ + n) * HD_) + l15];
                dp[0]  = f2bf(y0);
                dp[16] = f2bf(y1);
                dp[32] = f2bf(y2);
                dp[48] = f2bf(y3);
            }
        }
    }
}

// ---------------------------------------------------------------------------
// Kernel 4: out = o @ W_proj + b_proj. 64x128 tile (512 blocks = 2/CU).
// ---------------------------------------------------------------------------
__global__ __launch_bounds__(256) void gemm_proj_kernel(
    const unsigned short* __restrict__ O,    // [4096][1024] bf16
    const unsigned short* __restrict__ Wt,   // [1024][1024] bf16 (W^T)
    const float* __restrict__ bias, float* __restrict__ out)
{
    __shared__ unsigned short As[64 * 32];
    __shared__ unsigned short Bs[128 * 32];
    const int t    = threadIdx.x;
    const int lane = t & 63;
    const int w    = t >> 6;
    const int l15  = lane & 15;
    const int quad = lane >> 4;
    const int row0 = blockIdx.y * 64;
    const int col0 = blockIdx.x * 128;
    size_t aOff = (size_t)(row0 + w * 16 + (lane >> 2)) * 1024 + (lane & 3) * 8;
    size_t bOff = (size_t)(col0 + w * 16 + (lane >> 2)) * 1024 + (lane & 3) * 8;
    floatx4 acc[4][2];
    #pragma unroll
    for (int i = 0; i < 4; ++i)
        #pragma unroll
        for (int j = 0; j < 2; ++j) acc[i][j] = floatx4{0.f, 0.f, 0.f, 0.f};
    for (int k0 = 0; k0 < 1024; k0 += 32) {
        g2l16(&O[aOff + k0], &As[(w * 16) * 32]);
        #pragma unroll
        for (int c = 0; c < 2; ++c)
            g2l16(&Wt[bOff + (size_t)c * 64 * 1024 + k0],
                  &Bs[(w * 16 + c * 64) * 32]);
        __syncthreads();
        short8 af[4], bf[2];
        #pragma unroll
        for (int i = 0; i < 4; ++i)
            af[i] = *(const short8*)&As[(i * 16 + l15) * 32 + quad * 8];
        #pragma unroll
        for (int j = 0; j < 2; ++j)
            bf[j] = *(const short8*)&Bs[(w * 32 + j * 16 + l15) * 32 + quad * 8];
        #pragma unroll
        for (int i = 0; i < 4; ++i)
            #pragma unroll
            for (int j = 0; j < 2; ++j)
                acc[i][j] = __builtin_amdgcn_mfma_f32_16x16x32_bf16(
                    af[i], bf[j], acc[i][j], 0, 0, 0);
        __syncthreads();
    }
    #pragma unroll
    for (int j = 0; j < 2; ++j) {
        const int gcol = col0 + w * 32 + j * 16 + l15;
        const float b = bias[gcol];
        #pragma unroll
        for (int i = 0; i < 4; ++i) {
            #pragma unroll
            for (int r = 0; r < 4; ++r) {
                const int grow = row0 + i * 16 + quad * 4 + r;
                out[(size_t)grow * 1024 + gcol] = acc[i][j][r] + b;
            }
        }
    }
}

// ---------------------------------------------------------------------------
// Kernel 3: flash attention v7 — v6b + Ks/Pb LDS OVERLAY.
// K (stride 72) and P (stride 136) share one 34.8 KB region; they are
// temporally disjoint (K consumed in S-phase, P written after) separated by
// an extra barrier. LDS 70.6 -> 51 KB => 3 blocks/CU = 12 waves/CU.
// 4 waves x 32 q-rows; fixed-ref exp2 softmax; reg-pipelined staging.
// ---------------------------------------------------------------------------
__global__ __launch_bounds__(256, 3) void flash_kernel(
    const unsigned short* __restrict__ qb, const unsigned short* __restrict__ kb,
    const unsigned short* __restrict__ vb, unsigned short* __restrict__ ob)
{
    __shared__ __align__(16) unsigned short KP[128 * 136];   // K(72) / Q,P,O(136)
    __shared__ __align__(16) unsigned short Vt[64 * 136];    // [d][kv]
    const int t    = threadIdx.x;
    const int lane = t & 63;
    const int w    = t >> 6;                 // wave 0..3
    const int l15  = lane & 15;
    const int quad = lane >> 4;
    const int q0   = blockIdx.x * 128;
    const int bh   = blockIdx.y;
    const unsigned short* Q = qb + (size_t)bh * N_ * HD_;
    const unsigned short* K = kb + (size_t)bh * N_ * HD_;
    const unsigned short* V = vb + (size_t)bh * N_ * HD_;

    // stage Q (128x64) into KP (stride 136): 256 thr x 4 reps
    {
        const int r = t >> 3, c = (t & 7) * 8;
        #pragma unroll
        for (int rep = 0; rep < 4; ++rep)
            *(short8*)&KP[(rep * 32 + r) * 136 + c] =
                *(const short8*)&Q[(size_t)(q0 + rep * 32 + r) * 64 + c];
    }
    __syncthreads();
    // Q fragments (B-operand): rows qg*64 + w*16 + l15, qg in {0,1}
    short8 qf[2][2];
    #pragma unroll
    for (int qg = 0; qg < 2; ++qg)
        #pragma unroll
        for (int kk = 0; kk < 2; ++kk)
            qf[qg][kk] = *(const short8*)
                &KP[(qg * 64 + w * 16 + l15) * 136 + kk * 32 + quad * 8];

    floatx4 acc[2][4];
    #pragma unroll
    for (int qg = 0; qg < 2; ++qg)
        #pragma unroll
        for (int dt = 0; dt < 4; ++dt) acc[qg][dt] = floatx4{0.f, 0.f, 0.f, 0.f};
    float l_part[2] = {0.f, 0.f};

    // staging coords: K thread owns (row, 32-col half); V thread owns
    // (kv pair, 16-d slab)
    const int kr = t & 127, kc = (t >> 7) * 32;
    const int vkv = (t & 63) * 2, vd = (t >> 6) * 16;

    // preload tile 0 into regs (K: 4 x short8 = full 32-col span)
    short8 kR[4], vR[4];
    #pragma unroll
    for (int c = 0; c < 4; ++c)
        kR[c] = *(const short8*)&K[(size_t)kr * 64 + kc + c * 8];
    vR[0] = *(const short8*)&V[(size_t)vkv * 64 + vd];
    vR[1] = *(const short8*)&V[(size_t)vkv * 64 + vd + 8];
    vR[2] = *(const short8*)&V[(size_t)(vkv + 1) * 64 + vd];
    vR[3] = *(const short8*)&V[(size_t)(vkv + 1) * 64 + vd + 8];

    for (int kt = 0; kt < N_; kt += 128) {
        __syncthreads();   // barrier A: prior iter's PV reads (P,Vt) complete
        // regs -> LDS: K into KP at stride 72 (overlays dead P region)
        #pragma unroll
        for (int c = 0; c < 4; ++c)
            *(short8*)&KP[kr * 72 + kc + c * 8] = kR[c];
        #pragma unroll
        for (int j = 0; j < 8; ++j) {
            unsigned int p0 = (unsigned int)(unsigned short)vR[0][j] |
                              ((unsigned int)(unsigned short)vR[2][j] << 16);
            unsigned int p1 = (unsigned int)(unsigned short)vR[1][j] |
                              ((unsigned int)(unsigned short)vR[3][j] << 16);
            *(unsigned int*)&Vt[(vd + j) * 136 + vkv]     = p0;
            *(unsigned int*)&Vt[(vd + 8 + j) * 136 + vkv] = p1;
        }
        __syncthreads();   // barrier B: staged tile visible
        // prefetch next tile into regs — latency overlaps compute below
        if (kt + 128 < N_) {
            const int kt2 = kt + 128;
            #pragma unroll
            for (int c = 0; c < 4; ++c)
                kR[c] = *(const short8*)&K[(size_t)(kt2 + kr) * 64 + kc + c * 8];
            vR[0] = *(const short8*)&V[(size_t)(kt2 + vkv) * 64 + vd];
            vR[1] = *(const short8*)&V[(size_t)(kt2 + vkv) * 64 + vd + 8];
            vR[2] = *(const short8*)&V[(size_t)(kt2 + vkv + 1) * 64 + vd];
            vR[3] = *(const short8*)&V[(size_t)(kt2 + vkv + 1) * 64 + vd + 8];
        }

        // S^T = K . Q^T : 8 kv-tiles of 16; each A-frag feeds both q-groups
        floatx4 sc[2][8];
        #pragma unroll
        for (int ct = 0; ct < 8; ++ct) {
            short8 a0 = *(const short8*)&KP[(ct * 16 + l15) * 72 + quad * 8];
            short8 a1 = *(const short8*)&KP[(ct * 16 + l15) * 72 + 32 + quad * 8];
            #pragma unroll
            for (int qg = 0; qg < 2; ++qg) {
                floatx4 r = {0.f, 0.f, 0.f, 0.f};
                r = __builtin_amdgcn_mfma_f32_16x16x32_bf16(a0, qf[qg][0], r, 0, 0, 0);
                r = __builtin_amdgcn_mfma_f32_16x16x32_bf16(a1, qf[qg][1], r, 0, 0, 0);
                sc[qg][ct] = r;
            }
        }
        __syncthreads();   // barrier C: all waves' K reads done; P may overlay

        // fixed-reference softmax: p = exp2(s), defer the sum
        #pragma unroll
        for (int qg = 0; qg < 2; ++qg) {
            const int prow = qg * 64 + w * 16 + l15;
            #pragma unroll
            for (int ct = 0; ct < 8; ++ct) {
                float p0 = __builtin_amdgcn_exp2f(sc[qg][ct][0]);
                float p1 = __builtin_amdgcn_exp2f(sc[qg][ct][1]);
                float p2 = __builtin_amdgcn_exp2f(sc[qg][ct][2]);
                float p3 = __builtin_amdgcn_exp2f(sc[qg][ct][3]);
                l_part[qg] += (p0 + p1) + (p2 + p3);
                uint2 pk;
                pk.x = pk2bf(p0, p1);
                pk.y = pk2bf(p2, p3);
                *(uint2*)&KP[prow * 136 + ct * 16 + quad * 4] = pk;
            }
        }
        asm volatile("" ::: "memory");

        // O^T += V^T . P : Vt A-frags shared across both q-groups
        #pragma unroll
        for (int kk = 0; kk < 4; ++kk) {
            short8 pbf[2];
            #pragma unroll
            for (int qg = 0; qg < 2; ++qg)
                pbf[qg] = *(const short8*)
                    &KP[(qg * 64 + w * 16 + l15) * 136 + kk * 32 + quad * 8];
            #pragma unroll
            for (int dt = 0; dt < 4; ++dt) {
                short8 va = *(const short8*)
                    &Vt[(dt * 16 + l15) * 136 + kk * 32 + quad * 8];
                #pragma unroll
                for (int qg = 0; qg < 2; ++qg)
                    acc[qg][dt] = __builtin_amdgcn_mfma_f32_16x16x32_bf16(
                        va, pbf[qg], acc[qg][dt], 0, 0, 0);
            }
        }
    }

    // denominators + epilogue: O^T regs -> KP[q][d], then coalesced copy-out
    asm volatile("" ::: "memory");
    __syncthreads();   // all PV reads done before O overlays P rows
    #pragma unroll
    for (int qg = 0; qg < 2; ++qg) {
        l_part[qg] += __shfl_xor(l_part[qg], 16);
        l_part[qg] += __shfl_xor(l_part[qg], 32);
        const float inv = 1.0f / l_part[qg];
        const int orow = qg * 64 + w * 16 + l15;
        #pragma unroll
        for (int dt = 0; dt < 4; ++dt) {
            uint2 o2;
            o2.x = pk2bf(acc[qg][dt][0] * inv, acc[qg][dt][1] * inv);
            o2.y = pk2bf(acc[qg][dt][2] * inv, acc[qg][dt][3] * inv);
            *(uint2*)&KP[orow * 136 + dt * 16 + quad * 4] = o2;
        }
    }
    __syncthreads();
    const int bidx = bh >> 4, h = bh & 15;
    {
        const int r = t >> 3, c = (t & 7) * 8;
        #pragma unroll
        for (int rep = 0; rep < 4; ++rep) {
            const int row = rep * 32 + r;
            *(short8*)&ob[((size_t)(bidx * N_ + q0 + row)) * C_ + h * 64 + c] =
                *(const short8*)&KP[row * 136 + c];
        }
    }
}

// ---------------------------------------------------------------------------
extern "C" void kernel_launch(void* const* d_in, const int* in_sizes, int n_in,
                              void* d_out, int out_size, void* d_ws, size_t ws_size,
                              hipStream_t stream) {
    const float* x      = (const float*)d_in[0];
    const float* W_qkv  = (const float*)d_in[1];
    const float* qn_w   = (const float*)d_in[2];
    const float* qn_b   = (const float*)d_in[3];
    const float* kn_w   = (const float*)d_in[4];
    const float* kn_b   = (const float*)d_in[5];
    const float* W_proj = (const float*)d_in[6];
    const float* b_proj = (const float*)d_in[7];
    float* out = (float*)d_out;

    unsigned short* qb  = (unsigned short*)d_ws;               // 3 x QSZ bf16
    unsigned short* kb  = qb + (size_t)QSZ;
    unsigned short* vb  = kb + (size_t)QSZ;
    unsigned short* ob  = vb + (size_t)QSZ;                    // [B,N,C] bf16
    unsigned short* xb  = ob + (size_t)B_ * N_ * C_;           // [4096][1024]
    unsigned short* wqt = xb + (size_t)B_ * N_ * C_;           // [3072][1024]
    unsigned short* wpt = wqt + (size_t)3 * C_ * C_;           // [1024][1024]

    pack_bf16_kernel<<<dim3((B_ * N_ * C_) / 1024), 256, 0, stream>>>(x, xb);
    transpose_pack2_kernel<<<dim3(128, 32), 256, 0, stream>>>(W_qkv, wqt, W_proj, wpt);
    gemm_qkv_kernel<<<dim3(24, 32), 256, 0, stream>>>(
        xb, wqt, qn_w, qn_b, kn_w, kn_b, qb, kb, vb);
    flash_kernel<<<dim3(N_ / 128, B_ * H_), 256, 0, stream>>>(qb, kb, vb, ob);
    gemm_proj_kernel<<<dim3(8, 64), 256, 0, stream>>>(ob, wpt, b_proj, out);
}

// Round 11
// 202.132 us; speedup vs baseline: 1.0090x; 1.0090x over previous
//
#include <hip/hip_runtime.h>
#include <hip/hip_bf16.h>

#define B_  2
#define N_  2048
#define C_  1024
#define H_  16
#define HD_ 64
#define QSZ (B_*N_*C_)       // elements per q/k/v buffer
#define QSCALE 0.18033688011112042f   // 0.125 * log2(e): softmax in exp2 domain

typedef __attribute__((ext_vector_type(8))) short short8;            // 8 bf16
typedef __attribute__((ext_vector_type(4))) float floatx4;

__device__ __forceinline__ unsigned short f2bf(float f) {
    unsigned int u = __builtin_bit_cast(unsigned int, f);
    u += 0x7fff + ((u >> 16) & 1);          // round-to-nearest-even
    return (unsigned short)(u >> 16);
}
// pack two fp32 -> two RNE bf16 in one u32 (lo = a, hi = b) via v_perm_b32
__device__ __forceinline__ unsigned int pk2bf(float a, float b) {
    unsigned int ua = __builtin_bit_cast(unsigned int, a);
    unsigned int ub = __builtin_bit_cast(unsigned int, b);
    ua += 0x7fff + ((ua >> 16) & 1);
    ub += 0x7fff + ((ub >> 16) & 1);
    return __builtin_amdgcn_perm(ub, ua, 0x07060302);
}

// async global->LDS, 16 B per lane; LDS dest = wave-uniform base + lane*16
__device__ __forceinline__ void g2l16(const void* g, void* l) {
    __builtin_amdgcn_global_load_lds(
        (const __attribute__((address_space(1))) void*)g,
        (__attribute__((address_space(3))) void*)l, 16, 0, 0);
}

// ---------------------------------------------------------------------------
// pack fp32 -> bf16, same layout
// ---------------------------------------------------------------------------
__global__ __launch_bounds__(256) void pack_bf16_kernel(
    const float* __restrict__ src, unsigned short* __restrict__ dst)
{
    const int i = blockIdx.x * 256 + threadIdx.x;
    float4 v = ((const float4*)src)[i];
    ushort4 o = {f2bf(v.x), f2bf(v.y), f2bf(v.z), f2bf(v.w)};
    ((ushort4*)dst)[i] = o;
}

// ---------------------------------------------------------------------------
// transpose + pack BOTH weights in one launch
// ---------------------------------------------------------------------------
__global__ __launch_bounds__(256) void transpose_pack2_kernel(
    const float* __restrict__ Wq, unsigned short* __restrict__ Wqt,
    const float* __restrict__ Wp, unsigned short* __restrict__ Wpt)
{
    __shared__ unsigned short tl[32][34];
    const bool isq = blockIdx.x < 96;
    const int bx = isq ? blockIdx.x : blockIdx.x - 96;
    const int Nd = isq ? 3072 : 1024;
    const float* W = isq ? Wq : Wp;
    unsigned short* Wt = isq ? Wqt : Wpt;
    const int r  = threadIdx.x >> 3;
    const int c4 = (threadIdx.x & 7) * 4;
    const int n0 = bx * 32, k0 = blockIdx.y * 32;
    float4 v = *(const float4*)&W[(size_t)(k0 + r) * Nd + n0 + c4];
    tl[r][c4 + 0] = f2bf(v.x); tl[r][c4 + 1] = f2bf(v.y);
    tl[r][c4 + 2] = f2bf(v.z); tl[r][c4 + 3] = f2bf(v.w);
    __syncthreads();
    ushort4 o = {tl[c4 + 0][r], tl[c4 + 1][r], tl[c4 + 2][r], tl[c4 + 3][r]};
    *(ushort4*)&Wt[(size_t)(n0 + r) * 1024 + k0 + c4] = o;
}

// ---------------------------------------------------------------------------
// bf16 MFMA GEMM core (m97 structure): 128x128 tile, BK=32, 4 waves
// ---------------------------------------------------------------------------
#define GEMM_CORE(A_, Bt_, Kd_, row0_, col0_)                                 \
    __shared__ unsigned short As[128 * 32];                                   \
    __shared__ unsigned short Bs[128 * 32];                                   \
    const int t    = threadIdx.x;                                             \
    const int lane = t & 63;                                                  \
    const int w    = t >> 6;                                                  \
    const int l15  = lane & 15;                                               \
    const int quad = lane >> 4;                                               \
    const int wm   = w >> 1, wn = w & 1;                                      \
    size_t aOff = (size_t)(row0_ + w * 16 + (lane >> 2)) * Kd_ + (lane & 3) * 8; \
    size_t bOff = (size_t)(col0_ + w * 16 + (lane >> 2)) * Kd_ + (lane & 3) * 8; \
    floatx4 acc[4][4];                                                        \
    _Pragma("unroll")                                                         \
    for (int i = 0; i < 4; ++i)                                               \
        _Pragma("unroll")                                                     \
        for (int j = 0; j < 4; ++j) acc[i][j] = floatx4{0.f, 0.f, 0.f, 0.f};  \
    for (int k0 = 0; k0 < Kd_; k0 += 32) {                                    \
        _Pragma("unroll")                                                     \
        for (int c = 0; c < 2; ++c) {                                         \
            g2l16(&A_[aOff + (size_t)c * 64 * Kd_ + k0],                      \
                  &As[(w * 16 + c * 64) * 32]);                               \
            g2l16(&Bt_[bOff + (size_t)c * 64 * Kd_ + k0],                     \
                  &Bs[(w * 16 + c * 64) * 32]);                               \
        }                                                                     \
        __syncthreads();                                                      \
        short8 af[4], bf[4];                                                  \
        _Pragma("unroll")                                                     \
        for (int i = 0; i < 4; ++i)                                           \
            af[i] = *(const short8*)&As[(wm * 64 + i * 16 + l15) * 32 + quad * 8]; \
        _Pragma("unroll")                                                     \
        for (int j = 0; j < 4; ++j)                                           \
            bf[j] = *(const short8*)&Bs[(wn * 64 + j * 16 + l15) * 32 + quad * 8]; \
        _Pragma("unroll")                                                     \
        for (int i = 0; i < 4; ++i)                                           \
            _Pragma("unroll")                                                 \
            for (int j = 0; j < 4; ++j)                                       \
                acc[i][j] = __builtin_amdgcn_mfma_f32_16x16x32_bf16(          \
                    af[i], bf[j], acc[i][j], 0, 0, 0);                        \
        __syncthreads();                                                      \
    }

// ---------------------------------------------------------------------------
// Kernel 1: qkv = x @ W_qkv with FUSED per-head LayerNorm on q,k (fp32 math
// on accumulators, before bf16 rounding). q scaled by 0.125*log2(e).
// ---------------------------------------------------------------------------
__global__ __launch_bounds__(256) void gemm_qkv_kernel(
    const unsigned short* __restrict__ X,    // [4096][1024] bf16
    const unsigned short* __restrict__ Wt,   // [3072][1024] bf16 (W^T)
    const float* __restrict__ qn_w, const float* __restrict__ qn_b,
    const float* __restrict__ kn_w, const float* __restrict__ kn_b,
    unsigned short* __restrict__ qb, unsigned short* __restrict__ kb,
    unsigned short* __restrict__ vb)
{
    const int row0 = blockIdx.y * 128;
    const int col0 = blockIdx.x * 128;
    GEMM_CORE(X, Wt, 1024, row0, col0)
    const int which = col0 >> 10;            // 0=q 1=k 2=v, uniform per block
    const int h = ((col0 & 1023) >> 6) + wn; // head index for this wave
    if (which == 2) {
        #pragma unroll
        for (int j = 0; j < 4; ++j) {
            const int d = j * 16 + l15;
            #pragma unroll
            for (int i = 0; i < 4; ++i) {
                #pragma unroll
                for (int r = 0; r < 4; ++r) {
                    const int grow = row0 + wm * 64 + i * 16 + quad * 4 + r;
                    const int bidx = grow >> 11, n = grow & 2047;
                    vb[(((size_t)(bidx * H_ + h) * N_ + n) * HD_) + d] =
                        f2bf(acc[i][j][r]);
                }
            }
        }
    } else {
        const float* wt = (which == 0) ? qn_w : kn_w;
        const float* bi = (which == 0) ? qn_b : kn_b;
        unsigned short* dstbuf = (which == 0) ? qb : kb;
        float w4[4], b4[4];
        #pragma unroll
        for (int j = 0; j < 4; ++j) {
            w4[j] = wt[j * 16 + l15];
            b4[j] = bi[j * 16 + l15];
        }
        #pragma unroll
        for (int i = 0; i < 4; ++i) {
            #pragma unroll
            for (int r = 0; r < 4; ++r) {
                float v0 = acc[i][0][r], v1 = acc[i][1][r],
                      v2 = acc[i][2][r], v3 = acc[i][3][r];
                float s = (v0 + v1) + (v2 + v3);
                #pragma unroll
                for (int o = 1; o < 16; o <<= 1) s += __shfl_xor(s, o);
                const float mu = s * (1.0f / 64.0f);
                const float d0 = v0 - mu, d1 = v1 - mu,
                            d2 = v2 - mu, d3 = v3 - mu;
                float s2 = (d0 * d0 + d1 * d1) + (d2 * d2 + d3 * d3);
                #pragma unroll
                for (int o = 1; o < 16; o <<= 1) s2 += __shfl_xor(s2, o);
                const float rstd = rsqrtf(s2 * (1.0f / 64.0f) + 1e-5f);
                float y0 = d0 * rstd * w4[0] + b4[0];
                float y1 = d1 * rstd * w4[1] + b4[1];
                float y2 = d2 * rstd * w4[2] + b4[2];
                float y3 = d3 * rstd * w4[3] + b4[3];
                if (which == 0) {
                    y0 *= QSCALE; y1 *= QSCALE; y2 *= QSCALE; y3 *= QSCALE;
                }
                const int grow = row0 + wm * 64 + i * 16 + quad * 4 + r;
                const int bidx = grow >> 11, n = grow & 2047;
                unsigned short* dp =
                    &dstbuf[(((size_t)(bidx * H_ + h) * N_ + n) * HD_) + l15];
                dp[0]  = f2bf(y0);
                dp[16] = f2bf(y1);
                dp[32] = f2bf(y2);
                dp[48] = f2bf(y3);
            }
        }
    }
}

// ---------------------------------------------------------------------------
// Kernel 4: out = o @ W_proj + b_proj. 64x128 tile (512 blocks = 2/CU).
// ---------------------------------------------------------------------------
__global__ __launch_bounds__(256) void gemm_proj_kernel(
    const unsigned short* __restrict__ O,    // [4096][1024] bf16
    const unsigned short* __restrict__ Wt,   // [1024][1024] bf16 (W^T)
    const float* __restrict__ bias, float* __restrict__ out)
{
    __shared__ unsigned short As[64 * 32];
    __shared__ unsigned short Bs[128 * 32];
    const int t    = threadIdx.x;
    const int lane = t & 63;
    const int w    = t >> 6;
    const int l15  = lane & 15;
    const int quad = lane >> 4;
    const int row0 = blockIdx.y * 64;
    const int col0 = blockIdx.x * 128;
    size_t aOff = (size_t)(row0 + w * 16 + (lane >> 2)) * 1024 + (lane & 3) * 8;
    size_t bOff = (size_t)(col0 + w * 16 + (lane >> 2)) * 1024 + (lane & 3) * 8;
    floatx4 acc[4][2];
    #pragma unroll
    for (int i = 0; i < 4; ++i)
        #pragma unroll
        for (int j = 0; j < 2; ++j) acc[i][j] = floatx4{0.f, 0.f, 0.f, 0.f};
    for (int k0 = 0; k0 < 1024; k0 += 32) {
        g2l16(&O[aOff + k0], &As[(w * 16) * 32]);
        #pragma unroll
        for (int c = 0; c < 2; ++c)
            g2l16(&Wt[bOff + (size_t)c * 64 * 1024 + k0],
                  &Bs[(w * 16 + c * 64) * 32]);
        __syncthreads();
        short8 af[4], bf[2];
        #pragma unroll
        for (int i = 0; i < 4; ++i)
            af[i] = *(const short8*)&As[(i * 16 + l15) * 32 + quad * 8];
        #pragma unroll
        for (int j = 0; j < 2; ++j)
            bf[j] = *(const short8*)&Bs[(w * 32 + j * 16 + l15) * 32 + quad * 8];
        #pragma unroll
        for (int i = 0; i < 4; ++i)
            #pragma unroll
            for (int j = 0; j < 2; ++j)
                acc[i][j] = __builtin_amdgcn_mfma_f32_16x16x32_bf16(
                    af[i], bf[j], acc[i][j], 0, 0, 0);
        __syncthreads();
    }
    #pragma unroll
    for (int j = 0; j < 2; ++j) {
        const int gcol = col0 + w * 32 + j * 16 + l15;
        const float b = bias[gcol];
        #pragma unroll
        for (int i = 0; i < 4; ++i) {
            #pragma unroll
            for (int r = 0; r < 4; ++r) {
                const int grow = row0 + i * 16 + quad * 4 + r;
                out[(size_t)grow * 1024 + gcol] = acc[i][j][r] + b;
            }
        }
    }
}

// ---------------------------------------------------------------------------
// Kernel 3: flash attention v8 — 2x2 q/kv wave split.
// Wave w owns q-half qg=w&1 (64 rows) x kv-half kvh=w>>1 (64 of 128-kv tile).
// Fixed-ref exp2 softmax (no max) makes kv partials directly addable:
// final O = (acc_kvh0 + acc_kvh1) / (l_kvh0 + l_kvh1), summed via LDS.
// K/Vt A-frag LDS reads per wave-iter: 16 (vs 32 in v7). No K/P overlay,
// 2 barriers/iter. P rows/cols are wave-private (qg x kvh) -> no hazards.
// LDS 71.2 KB -> 2 blocks/CU (= grid limit anyway).
// ---------------------------------------------------------------------------
__global__ __launch_bounds__(256, 2) void flash_kernel(
    const unsigned short* __restrict__ qb, const unsigned short* __restrict__ kb,
    const unsigned short* __restrict__ vb, unsigned short* __restrict__ ob)
{
    __shared__ __align__(16) unsigned short Ks[128 * 72];
    __shared__ __align__(16) unsigned short Vt[64 * 136];    // [d][kv]
    __shared__ __align__(16) unsigned short Pb[128 * 136];   // Q stage -> P -> O(fp32)
    __shared__ float Lb[128];
    const int t    = threadIdx.x;
    const int lane = t & 63;
    const int w    = t >> 6;                 // wave 0..3
    const int qg   = w & 1;                  // q half (64 rows)
    const int kvh  = w >> 1;                 // kv half (64 of 128)
    const int l15  = lane & 15;
    const int quad = lane >> 4;
    const int q0   = blockIdx.x * 128;
    const int bh   = blockIdx.y;
    const unsigned short* Q = qb + (size_t)bh * N_ * HD_;
    const unsigned short* K = kb + (size_t)bh * N_ * HD_;
    const unsigned short* V = vb + (size_t)bh * N_ * HD_;

    // stage Q (128x64) into Pb: 256 thr x 4 reps
    {
        const int r = t >> 3, c = (t & 7) * 8;
        #pragma unroll
        for (int rep = 0; rep < 4; ++rep)
            *(short8*)&Pb[(rep * 32 + r) * 136 + c] =
                *(const short8*)&Q[(size_t)(q0 + rep * 32 + r) * 64 + c];
    }
    __syncthreads();
    // Q fragments (B-operand): own 4 q-subtiles (rows qg*64 + qt*16 + l15)
    short8 qf[4][2];
    #pragma unroll
    for (int qt = 0; qt < 4; ++qt)
        #pragma unroll
        for (int kk = 0; kk < 2; ++kk)
            qf[qt][kk] = *(const short8*)
                &Pb[(qg * 64 + qt * 16 + l15) * 136 + kk * 32 + quad * 8];

    floatx4 acc[4][4];
    #pragma unroll
    for (int qt = 0; qt < 4; ++qt)
        #pragma unroll
        for (int dt = 0; dt < 4; ++dt) acc[qt][dt] = floatx4{0.f, 0.f, 0.f, 0.f};
    float l_part[4] = {0.f, 0.f, 0.f, 0.f};

    // staging coords (full 128-kv tile staged cooperatively, as v6b)
    const int kr = t & 127, kc = (t >> 7) * 32;
    const int vkv = (t & 63) * 2, vd = (t >> 6) * 16;

    short8 kR[4], vR[4];
    #pragma unroll
    for (int c = 0; c < 4; ++c)
        kR[c] = *(const short8*)&K[(size_t)kr * 64 + kc + c * 8];
    vR[0] = *(const short8*)&V[(size_t)vkv * 64 + vd];
    vR[1] = *(const short8*)&V[(size_t)vkv * 64 + vd + 8];
    vR[2] = *(const short8*)&V[(size_t)(vkv + 1) * 64 + vd];
    vR[3] = *(const short8*)&V[(size_t)(vkv + 1) * 64 + vd + 8];

    for (int kt = 0; kt < N_; kt += 128) {
        __syncthreads();   // barrier A: prior iter's Ks/Vt reads complete
        #pragma unroll
        for (int c = 0; c < 4; ++c)
            *(short8*)&Ks[kr * 72 + kc + c * 8] = kR[c];
        #pragma unroll
        for (int j = 0; j < 8; ++j) {
            unsigned int p0 = (unsigned int)(unsigned short)vR[0][j] |
                              ((unsigned int)(unsigned short)vR[2][j] << 16);
            unsigned int p1 = (unsigned int)(unsigned short)vR[1][j] |
                              ((unsigned int)(unsigned short)vR[3][j] << 16);
            *(unsigned int*)&Vt[(vd + j) * 136 + vkv]     = p0;
            *(unsigned int*)&Vt[(vd + 8 + j) * 136 + vkv] = p1;
        }
        __syncthreads();   // barrier B: staged tile visible
        // prefetch next tile into regs — latency overlaps compute below
        if (kt + 128 < N_) {
            const int kt2 = kt + 128;
            #pragma unroll
            for (int c = 0; c < 4; ++c)
                kR[c] = *(const short8*)&K[(size_t)(kt2 + kr) * 64 + kc + c * 8];
            vR[0] = *(const short8*)&V[(size_t)(kt2 + vkv) * 64 + vd];
            vR[1] = *(const short8*)&V[(size_t)(kt2 + vkv) * 64 + vd + 8];
            vR[2] = *(const short8*)&V[(size_t)(kt2 + vkv + 1) * 64 + vd];
            vR[3] = *(const short8*)&V[(size_t)(kt2 + vkv + 1) * 64 + vd + 8];
        }

        // S^T + fused fixed-ref softmax: own 4 kv-subtiles x own 4 q-subtiles
        #pragma unroll
        for (int ci = 0; ci < 4; ++ci) {
            const int ct = kvh * 4 + ci;
            short8 a0 = *(const short8*)&Ks[(ct * 16 + l15) * 72 + quad * 8];
            short8 a1 = *(const short8*)&Ks[(ct * 16 + l15) * 72 + 32 + quad * 8];
            #pragma unroll
            for (int qt = 0; qt < 4; ++qt) {
                floatx4 s = {0.f, 0.f, 0.f, 0.f};
                s = __builtin_amdgcn_mfma_f32_16x16x32_bf16(a0, qf[qt][0], s, 0, 0, 0);
                s = __builtin_amdgcn_mfma_f32_16x16x32_bf16(a1, qf[qt][1], s, 0, 0, 0);
                const float p0 = __builtin_amdgcn_exp2f(s[0]);
                const float p1 = __builtin_amdgcn_exp2f(s[1]);
                const float p2 = __builtin_amdgcn_exp2f(s[2]);
                const float p3 = __builtin_amdgcn_exp2f(s[3]);
                l_part[qt] += (p0 + p1) + (p2 + p3);
                uint2 pk;
                pk.x = pk2bf(p0, p1);
                pk.y = pk2bf(p2, p3);
                *(uint2*)&Pb[(qg * 64 + qt * 16 + l15) * 136 + ct * 16 + quad * 4] = pk;
            }
        }
        asm volatile("" ::: "memory");   // same-wave P write -> read ordering

        // O^T partial += V^T[own kv half] . P[own rows, own kv half]
        #pragma unroll
        for (int kk2 = 0; kk2 < 2; ++kk2) {
            const int kk = kvh * 2 + kk2;
            short8 pbf[4];
            #pragma unroll
            for (int qt = 0; qt < 4; ++qt)
                pbf[qt] = *(const short8*)
                    &Pb[(qg * 64 + qt * 16 + l15) * 136 + kk * 32 + quad * 8];
            #pragma unroll
            for (int dt = 0; dt < 4; ++dt) {
                short8 va = *(const short8*)
                    &Vt[(dt * 16 + l15) * 136 + kk * 32 + quad * 8];
                #pragma unroll
                for (int qt = 0; qt < 4; ++qt)
                    acc[qt][dt] = __builtin_amdgcn_mfma_f32_16x16x32_bf16(
                        va, pbf[qt], acc[qt][dt], 0, 0, 0);
            }
        }
    }

    // cross-wave reduction (kvh 0 + kvh 1) via fp32 view of Pb, then output
    #pragma unroll
    for (int qt = 0; qt < 4; ++qt) {
        l_part[qt] += __shfl_xor(l_part[qt], 16);
        l_part[qt] += __shfl_xor(l_part[qt], 32);
    }
    __syncthreads();                      // all PV reads of Pb done
    float* Pf = (float*)Pb;               // 128 rows x stride 68 fp32 (34816 B)
    if (kvh == 0) {
        #pragma unroll
        for (int qt = 0; qt < 4; ++qt) {
            const int q = qg * 64 + qt * 16 + l15;
            #pragma unroll
            for (int dt = 0; dt < 4; ++dt)
                #pragma unroll
                for (int r = 0; r < 4; ++r)
                    Pf[q * 68 + dt * 16 + quad * 4 + r] = acc[qt][dt][r];
            if (quad == 0) Lb[q] = l_part[qt];
        }
    }
    __syncthreads();
    if (kvh == 1) {
        #pragma unroll
        for (int qt = 0; qt < 4; ++qt) {
            const int q = qg * 64 + qt * 16 + l15;
            #pragma unroll
            for (int dt = 0; dt < 4; ++dt)
                #pragma unroll
                for (int r = 0; r < 4; ++r)
                    Pf[q * 68 + dt * 16 + quad * 4 + r] += acc[qt][dt][r];
            if (quad == 0) Lb[q] += l_part[qt];
        }
    }
    __syncthreads();
    // write out: thread t handles row t>>1, 32-d half (t&1)
    {
        const int orow = t >> 1, oc = (t & 1) * 32;
        const float inv = 1.0f / Lb[orow];
        const int bidx = bh >> 4, h = bh & 15;
        unsigned short* dst =
            &ob[((size_t)(bidx * N_ + q0 + orow)) * C_ + h * 64 + oc];
        #pragma unroll
        for (int k = 0; k < 4; ++k) {
            float4 f0 = *(float4*)&Pf[orow * 68 + oc + k * 8];
            float4 f1 = *(float4*)&Pf[orow * 68 + oc + k * 8 + 4];
            uint4 u;
            u.x = pk2bf(f0.x * inv, f0.y * inv);
            u.y = pk2bf(f0.z * inv, f0.w * inv);
            u.z = pk2bf(f1.x * inv, f1.y * inv);
            u.w = pk2bf(f1.z * inv, f1.w * inv);
            *(uint4*)&dst[k * 8] = u;
        }
    }
}

// ---------------------------------------------------------------------------
extern "C" void kernel_launch(void* const* d_in, const int* in_sizes, int n_in,
                              void* d_out, int out_size, void* d_ws, size_t ws_size,
                              hipStream_t stream) {
    const float* x      = (const float*)d_in[0];
    const float* W_qkv  = (const float*)d_in[1];
    const float* qn_w   = (const float*)d_in[2];
    const float* qn_b   = (const float*)d_in[3];
    const float* kn_w   = (const float*)d_in[4];
    const float* kn_b   = (const float*)d_in[5];
    const float* W_proj = (const float*)d_in[6];
    const float* b_proj = (const float*)d_in[7];
    float* out = (float*)d_out;

    unsigned short* qb  = (unsigned short*)d_ws;               // 3 x QSZ bf16
    unsigned short* kb  = qb + (size_t)QSZ;
    unsigned short* vb  = kb + (size_t)QSZ;
    unsigned short* ob  = vb + (size_t)QSZ;                    // [B,N,C] bf16
    unsigned short* xb  = ob + (size_t)B_ * N_ * C_;           // [4096][1024]
    unsigned short* wqt = xb + (size_t)B_ * N_ * C_;           // [3072][1024]
    unsigned short* wpt = wqt + (size_t)3 * C_ * C_;           // [1024][1024]

    pack_bf16_kernel<<<dim3((B_ * N_ * C_) / 1024), 256, 0, stream>>>(x, xb);
    transpose_pack2_kernel<<<dim3(128, 32), 256, 0, stream>>>(W_qkv, wqt, W_proj, wpt);
    gemm_qkv_kernel<<<dim3(24, 32), 256, 0, stream>>>(
        xb, wqt, qn_w, qn_b, kn_w, kn_b, qb, kb, vb);
    flash_kernel<<<dim3(N_ / 128, B_ * H_), 256, 0, stream>>>(qb, kb, vb, ob);
    gemm_proj_kernel<<<dim3(8, 64), 256, 0, stream>>>(ob, wpt, b_proj, out);
}